// Round 3
// baseline (462.709 us; speedup 1.0000x reference)
//
#include <hip/hip_runtime.h>
#include <hip/hip_cooperative_groups.h>
#include <math.h>
#include <stdint.h>

namespace cg = cooperative_groups;

typedef unsigned int u32;
typedef unsigned long long u64;

#define BLOCK 256

// Cooperative (single-kernel) config: 1024 blocks == 256 CU x 4 blocks/CU
// at __launch_bounds__(256,4) -> guaranteed co-residency for grid.sync().
#define ITEMS_C 32
#define CHUNK_C (BLOCK * ITEMS_C)  // 8192

// Fallback (3-kernel) config — proven round-2 path.
#define ITEMS_F 16
#define CHUNK_F (BLOCK * ITEMS_F)  // 4096

// ---------------------------------------------------------------------------
// Fused cooperative kernel.
// Phase 1: labels (read ONCE, kept packed in regs) -> ballots -> per-block
//          ranks in LDS -> block hist to global; prefetch first data batch.
// grid.sync()
// Phase 2: global prefix from hist (L2-hot) -> pipelined scatter (4x8 float4)
//          -> fused analytic label write -> loss; last block finalizes loss.
// ---------------------------------------------------------------------------
__global__ void __launch_bounds__(BLOCK, 4)
fused_kernel(const float4* __restrict__ data, const int* __restrict__ labels,
             int N, int nb, u32* __restrict__ hist,
             float4* __restrict__ out_data, float* __restrict__ out_label,
             double* __restrict__ acc, u32* __restrict__ done,
             float* __restrict__ out_loss) {
    __shared__ u32 s_pre[ITEMS_C][4][4];  // [iter][wave][class] -> excl prefix
    __shared__ u32 s_red[4][8];           // [wave][bef.xyzw, tot.xyzw]
    __shared__ u32 s_bc[8];               // sb0..sb3, cb1..cb3
    __shared__ double s_w[4];
    int tid = threadIdx.x;
    int lane = tid & 63;
    int wave = tid >> 6;
    int b = blockIdx.x;
    int base = b * CHUNK_C;

    if (b == 0 && tid == 0) { *acc = 0.0; *done = 0u; }

    // Validity mask (bit j: element base + j*BLOCK + tid in range).
    u32 vmask;
    {
        int rem = N - base - tid;
        if (rem >= (ITEMS_C - 1) * BLOCK + 1) {
            vmask = 0xFFFFFFFFu;
        } else {
            vmask = 0;
#pragma unroll
            for (int j = 0; j < ITEMS_C; ++j)
                vmask |= (u32)(j * BLOCK < rem) << j;
        }
    }

    // Labels: the ONLY read of the label array in the whole pipeline.
    int lab[ITEMS_C];
#pragma unroll
    for (int j = 0; j < ITEMS_C; ++j) {
        int idx = base + j * BLOCK + tid;
        lab[j] = ((vmask >> j) & 1) ? labels[idx] : 0;
    }

    // Ballots: per-(iter,wave) class counts to LDS + per-lane rank in regs.
    u64 ltm = (1ULL << lane) - 1ULL;
    u32 pk0 = 0, pk1 = 0;                 // 2-bit packed labels
    u32 preP[ITEMS_C / 4] = {0, 0, 0, 0, 0, 0, 0, 0};
#pragma unroll
    for (int j = 0; j < ITEMS_C; ++j) {
        bool valid = (vmask >> j) & 1;
        int l = lab[j];
        if (j < 16) pk0 |= (u32)l << (2 * j);
        else        pk1 |= (u32)l << (2 * (j - 16));
        u64 m0 = __ballot(valid && l == 0);
        u64 m1 = __ballot(valid && l == 1);
        u64 m2 = __ballot(valid && l == 2);
        u64 m3 = __ballot(valid && l == 3);
        if (lane == 0) {
            s_pre[j][wave][0] = (u32)__popcll(m0);
            s_pre[j][wave][1] = (u32)__popcll(m1);
            s_pre[j][wave][2] = (u32)__popcll(m2);
            s_pre[j][wave][3] = (u32)__popcll(m3);
        }
        u64 mm = (l == 0) ? m0 : (l == 1) ? m1 : (l == 2) ? m2 : m3;
        preP[j >> 2] |= ((u32)__popcll(mm & ltm)) << (8 * (j & 3));
    }
    __syncthreads();

    // Scan: wave w owns class w. 128 entries in (j,wave) order, 2 per lane.
    {
        int c = wave;
        int E0 = 2 * lane, E1 = 2 * lane + 1;
        u32 x0 = s_pre[E0 >> 2][E0 & 3][c];
        u32 x1 = s_pre[E1 >> 2][E1 & 3][c];
        u32 pair = x0 + x1;
        u32 inc = pair;
#pragma unroll
        for (int off = 1; off < 64; off <<= 1) {
            u32 v = (u32)__shfl_up((int)inc, off, 64);
            if (lane >= off) inc += v;
        }
        u32 excl = inc - pair;
        s_pre[E0 >> 2][E0 & 3][c] = excl;
        s_pre[E1 >> 2][E1 & 3][c] = excl + x0;
        if (lane == 63) hist[b * 4 + c] = inc;  // block total for class c
    }

    // Prefetch first data batch so it flies under the grid barrier.
    float4 rA[8];
#pragma unroll
    for (int k = 0; k < 8; ++k) {
        if ((vmask >> k) & 1) rA[k] = data[base + k * BLOCK + tid];
    }

    cg::this_grid().sync();

    // Global prefix over block histograms (tiny, L2-hot: nb*16 B).
    uint4 bef = make_uint4(0, 0, 0, 0), tot = make_uint4(0, 0, 0, 0);
    {
        const uint4* h4 = (const uint4*)hist;
        for (int bb = tid; bb < nb; bb += BLOCK) {
            uint4 h = h4[bb];
            tot.x += h.x; tot.y += h.y; tot.z += h.z; tot.w += h.w;
            if (bb < b) {
                bef.x += h.x; bef.y += h.y; bef.z += h.z; bef.w += h.w;
            }
        }
    }
#pragma unroll
    for (int off = 32; off > 0; off >>= 1) {
        bef.x += (u32)__shfl_down((int)bef.x, off, 64);
        bef.y += (u32)__shfl_down((int)bef.y, off, 64);
        bef.z += (u32)__shfl_down((int)bef.z, off, 64);
        bef.w += (u32)__shfl_down((int)bef.w, off, 64);
        tot.x += (u32)__shfl_down((int)tot.x, off, 64);
        tot.y += (u32)__shfl_down((int)tot.y, off, 64);
        tot.z += (u32)__shfl_down((int)tot.z, off, 64);
        tot.w += (u32)__shfl_down((int)tot.w, off, 64);
    }
    if (lane == 0) {
        s_red[wave][0] = bef.x; s_red[wave][1] = bef.y;
        s_red[wave][2] = bef.z; s_red[wave][3] = bef.w;
        s_red[wave][4] = tot.x; s_red[wave][5] = tot.y;
        s_red[wave][6] = tot.z; s_red[wave][7] = tot.w;
    }
    __syncthreads();
    if (tid == 0) {
        u32 B0 = s_red[0][0] + s_red[1][0] + s_red[2][0] + s_red[3][0];
        u32 B1 = s_red[0][1] + s_red[1][1] + s_red[2][1] + s_red[3][1];
        u32 B2 = s_red[0][2] + s_red[1][2] + s_red[2][2] + s_red[3][2];
        u32 B3 = s_red[0][3] + s_red[1][3] + s_red[2][3] + s_red[3][3];
        u32 T0 = s_red[0][4] + s_red[1][4] + s_red[2][4] + s_red[3][4];
        u32 T1 = s_red[0][5] + s_red[1][5] + s_red[2][5] + s_red[3][5];
        u32 T2 = s_red[0][6] + s_red[1][6] + s_red[2][6] + s_red[3][6];
        u32 cb1 = T0, cb2 = T0 + T1, cb3 = T0 + T1 + T2;
        s_bc[0] = B0;       s_bc[1] = cb1 + B1;
        s_bc[2] = cb2 + B2; s_bc[3] = cb3 + B3;
        s_bc[4] = cb1; s_bc[5] = cb2; s_bc[6] = cb3;
    }
    __syncthreads();

    u32 sb0 = s_bc[0], sb1 = s_bc[1], sb2 = s_bc[2], sb3 = s_bc[3];
    u32 cb1 = s_bc[4], cb2 = s_bc[5], cb3 = s_bc[6];

    const float INV_M = 0.249999375f;  // 1/4.00001
    float loss = 0.f;

#define PROCESS(R, J0)                                                        \
    _Pragma("unroll")                                                         \
    for (int k = 0; k < 8; ++k) {                                             \
        int j = (J0) + k;                                                     \
        if ((vmask >> j) & 1) {                                               \
            int l = (int)((((j) < 16) ? (pk0 >> (2 * j))                      \
                                      : (pk1 >> (2 * (j - 16)))) & 3u);       \
            u32 pre = (preP[j >> 2] >> (8 * (j & 3))) & 255u;                 \
            u32 bb2 = (l == 0) ? sb0 : (l == 1) ? sb1                         \
                                     : (l == 2) ? sb2 : sb3;                  \
            u32 dst = bb2 + s_pre[j][wave][l] + pre;                          \
            float4 rr = R[k];                                                 \
            float v = (l == 0) ? rr.x : (l == 1) ? rr.y                       \
                                      : (l == 2) ? rr.z : rr.w;               \
            float adj = (v > 0.f) ? (v * INV_M - 0.5f)                        \
                                  : (v * 4.00001f - 0.5f);                    \
            if (l == 0) rr.x = adj;                                           \
            else if (l == 1) rr.y = adj;                                      \
            else if (l == 2) rr.z = adj;                                      \
            else rr.w = adj;                                                  \
            out_data[dst] = rr;                                               \
            float mx = fmaxf(fmaxf(rr.x, rr.y), fmaxf(rr.z, rr.w));           \
            float se = __expf(rr.x - mx) + __expf(rr.y - mx) +                \
                       __expf(rr.z - mx) + __expf(rr.w - mx);                 \
            loss += (mx + __logf(se)) - adj;                                  \
        }                                                                     \
    }

    // Pipelined batches: issue next batch before processing current.
    float4 rB[8];
#pragma unroll
    for (int k = 0; k < 8; ++k) {
        int j = 8 + k;
        if ((vmask >> j) & 1) rB[k] = data[base + j * BLOCK + tid];
    }
    PROCESS(rA, 0)
#pragma unroll
    for (int k = 0; k < 8; ++k) {
        int j = 16 + k;
        if ((vmask >> j) & 1) rA[k] = data[base + j * BLOCK + tid];
    }
    PROCESS(rB, 8)
#pragma unroll
    for (int k = 0; k < 8; ++k) {
        int j = 24 + k;
        if ((vmask >> j) & 1) rB[k] = data[base + j * BLOCK + tid];
    }
    PROCESS(rA, 16)
    PROCESS(rB, 24)
#undef PROCESS

    // Fused analytic label write for this block's range (2048 float4).
    {
        int t4base = base >> 2;
#pragma unroll
        for (int k = 0; k < 8; ++k) {
            int t4 = t4base + k * BLOCK + tid;
            int j0 = t4 * 4;
            if (j0 + 3 < N) {
                u32 j0u = (u32)j0;
                float4 rl;
                rl.x = (float)((j0u >= cb1) + (j0u >= cb2) + (j0u >= cb3));
                rl.y = (float)((j0u + 1 >= cb1) + (j0u + 1 >= cb2) + (j0u + 1 >= cb3));
                rl.z = (float)((j0u + 2 >= cb1) + (j0u + 2 >= cb2) + (j0u + 2 >= cb3));
                rl.w = (float)((j0u + 3 >= cb1) + (j0u + 3 >= cb2) + (j0u + 3 >= cb3));
                ((float4*)out_label)[t4] = rl;
            } else {
                for (int q = 0; q < 4; ++q) {
                    int jj = j0 + q;
                    if (jj >= 0 && jj < N) {
                        u32 ju = (u32)jj;
                        out_label[jj] =
                            (float)((ju >= cb1) + (ju >= cb2) + (ju >= cb3));
                    }
                }
            }
        }
    }

    // Loss: block-reduce in double, one atomic per block; last block writes.
    double d = (double)loss;
#pragma unroll
    for (int off = 32; off > 0; off >>= 1) d += __shfl_down(d, off, 64);
    if (lane == 0) s_w[wave] = d;
    __syncthreads();
    if (tid == 0) {
        atomicAdd(acc, s_w[0] + s_w[1] + s_w[2] + s_w[3]);
        __threadfence();
        u32 old = atomicAdd(done, 1u);
        if (old == (u32)(gridDim.x - 1)) {
            double tl = atomicAdd(acc, 0.0);  // coherent read of final sum
            *out_loss = (float)(tl / (double)N);
        }
    }
}

// ===========================================================================
// Fallback path (proven round-2 three-kernel pipeline, CHUNK_F = 4096).
// Used only if the cooperative launch is rejected.
// ===========================================================================
__global__ void __launch_bounds__(BLOCK)
hist_kernel(const int* __restrict__ labels, int N,
            u32* __restrict__ hist, u32* __restrict__ plab,
            double* __restrict__ acc) {
    __shared__ u32 s_cnt[4][4];
    int tid = threadIdx.x;
    int lane = tid & 63;
    int wave = tid >> 6;
    int base = blockIdx.x * CHUNK_F;
    u32 packed = 0;
    u32 c0 = 0, c1 = 0, c2 = 0, c3 = 0;
#pragma unroll
    for (int j = 0; j < ITEMS_F; ++j) {
        int idx = base + j * BLOCK + tid;
        bool valid = idx < N;
        int l = valid ? labels[idx] : 0;
        packed |= (u32)l << (2 * j);
        c0 += (valid && l == 0);
        c1 += (valid && l == 1);
        c2 += (valid && l == 2);
        c3 += (valid && l == 3);
    }
    plab[blockIdx.x * BLOCK + tid] = packed;
#pragma unroll
    for (int off = 32; off > 0; off >>= 1) {
        c0 += (u32)__shfl_down((int)c0, off, 64);
        c1 += (u32)__shfl_down((int)c1, off, 64);
        c2 += (u32)__shfl_down((int)c2, off, 64);
        c3 += (u32)__shfl_down((int)c3, off, 64);
    }
    if (lane == 0) {
        s_cnt[wave][0] = c0; s_cnt[wave][1] = c1;
        s_cnt[wave][2] = c2; s_cnt[wave][3] = c3;
    }
    __syncthreads();
    if (tid < 4)
        hist[blockIdx.x * 4 + tid] =
            s_cnt[0][tid] + s_cnt[1][tid] + s_cnt[2][tid] + s_cnt[3][tid];
    if (blockIdx.x == 0 && tid == 0) *acc = 0.0;
}

__global__ void __launch_bounds__(BLOCK)
sort_kernel(const float4* __restrict__ data, const u32* __restrict__ plab,
            int N, int nb, const u32* __restrict__ hist,
            float4* __restrict__ out_data, float* __restrict__ out_label,
            double* __restrict__ acc) {
    __shared__ u32 s_pre[ITEMS_F][4][4];
    __shared__ u32 s_red[4][8];
    __shared__ u32 s_bc[8];
    __shared__ double s_w[4];
    int tid = threadIdx.x;
    int lane = tid & 63;
    int wave = tid >> 6;
    int base = blockIdx.x * CHUNK_F;

    u32 packed = plab[blockIdx.x * BLOCK + tid];
    u32 vmask;
    {
        int rem = N - base - tid;
        if (rem >= (ITEMS_F - 1) * BLOCK + 1) vmask = 0xFFFFu;
        else {
            vmask = 0;
#pragma unroll
            for (int j = 0; j < ITEMS_F; ++j)
                vmask |= (u32)(j * BLOCK < rem) << j;
        }
    }

    uint4 bef = make_uint4(0, 0, 0, 0), tot = make_uint4(0, 0, 0, 0);
    {
        const uint4* h4 = (const uint4*)hist;
        u32 myb = blockIdx.x;
        for (int bb = tid; bb < nb; bb += BLOCK) {
            uint4 h = h4[bb];
            tot.x += h.x; tot.y += h.y; tot.z += h.z; tot.w += h.w;
            if ((u32)bb < myb) {
                bef.x += h.x; bef.y += h.y; bef.z += h.z; bef.w += h.w;
            }
        }
    }

    float4 r0[8];
#pragma unroll
    for (int k = 0; k < 8; ++k) {
        int idx = base + k * BLOCK + tid;
        if ((vmask >> k) & 1) r0[k] = data[idx];
    }

    u64 ltm = (1ULL << lane) - 1ULL;
    u32 preP[ITEMS_F / 4] = {0, 0, 0, 0};
#pragma unroll
    for (int j = 0; j < ITEMS_F; ++j) {
        bool valid = (vmask >> j) & 1;
        int l = (packed >> (2 * j)) & 3;
        u64 m0 = __ballot(valid && l == 0);
        u64 m1 = __ballot(valid && l == 1);
        u64 m2 = __ballot(valid && l == 2);
        u64 m3 = __ballot(valid && l == 3);
        if (lane == 0) {
            s_pre[j][wave][0] = (u32)__popcll(m0);
            s_pre[j][wave][1] = (u32)__popcll(m1);
            s_pre[j][wave][2] = (u32)__popcll(m2);
            s_pre[j][wave][3] = (u32)__popcll(m3);
        }
        u64 mm = (l == 0) ? m0 : (l == 1) ? m1 : (l == 2) ? m2 : m3;
        preP[j >> 2] |= ((u32)__popcll(mm & ltm)) << (8 * (j & 3));
    }

#pragma unroll
    for (int off = 32; off > 0; off >>= 1) {
        bef.x += (u32)__shfl_down((int)bef.x, off, 64);
        bef.y += (u32)__shfl_down((int)bef.y, off, 64);
        bef.z += (u32)__shfl_down((int)bef.z, off, 64);
        bef.w += (u32)__shfl_down((int)bef.w, off, 64);
        tot.x += (u32)__shfl_down((int)tot.x, off, 64);
        tot.y += (u32)__shfl_down((int)tot.y, off, 64);
        tot.z += (u32)__shfl_down((int)tot.z, off, 64);
        tot.w += (u32)__shfl_down((int)tot.w, off, 64);
    }
    if (lane == 0) {
        s_red[wave][0] = bef.x; s_red[wave][1] = bef.y;
        s_red[wave][2] = bef.z; s_red[wave][3] = bef.w;
        s_red[wave][4] = tot.x; s_red[wave][5] = tot.y;
        s_red[wave][6] = tot.z; s_red[wave][7] = tot.w;
    }
    __syncthreads();

    {
        int c = wave;
        int e = lane;
        u32 x = s_pre[e >> 2][e & 3][c];
        u32 orig = x;
#pragma unroll
        for (int off = 1; off < 64; off <<= 1) {
            u32 v = (u32)__shfl_up((int)x, off, 64);
            if (lane >= off) x += v;
        }
        s_pre[e >> 2][e & 3][c] = x - orig;
    }
    if (tid == 0) {
        u32 B0 = s_red[0][0] + s_red[1][0] + s_red[2][0] + s_red[3][0];
        u32 B1 = s_red[0][1] + s_red[1][1] + s_red[2][1] + s_red[3][1];
        u32 B2 = s_red[0][2] + s_red[1][2] + s_red[2][2] + s_red[3][2];
        u32 B3 = s_red[0][3] + s_red[1][3] + s_red[2][3] + s_red[3][3];
        u32 T0 = s_red[0][4] + s_red[1][4] + s_red[2][4] + s_red[3][4];
        u32 T1 = s_red[0][5] + s_red[1][5] + s_red[2][5] + s_red[3][5];
        u32 T2 = s_red[0][6] + s_red[1][6] + s_red[2][6] + s_red[3][6];
        u32 cb1 = T0, cb2 = T0 + T1, cb3 = T0 + T1 + T2;
        s_bc[0] = B0;       s_bc[1] = cb1 + B1;
        s_bc[2] = cb2 + B2; s_bc[3] = cb3 + B3;
        s_bc[4] = cb1; s_bc[5] = cb2; s_bc[6] = cb3;
    }
    __syncthreads();

    u32 sb0 = s_bc[0], sb1 = s_bc[1], sb2 = s_bc[2], sb3 = s_bc[3];
    u32 cb1 = s_bc[4], cb2 = s_bc[5], cb3 = s_bc[6];

    float4 r1[8];
#pragma unroll
    for (int k = 0; k < 8; ++k) {
        int j = 8 + k;
        int idx = base + j * BLOCK + tid;
        if ((vmask >> j) & 1) r1[k] = data[idx];
    }

    const float INV_M = 0.249999375f;
    float loss = 0.f;
#pragma unroll
    for (int k = 0; k < 8; ++k) {
        int j = k;
        if ((vmask >> j) & 1) {
            int l = (packed >> (2 * j)) & 3;
            u32 pre = (preP[j >> 2] >> (8 * (j & 3))) & 255u;
            u32 bb = (l == 0) ? sb0 : (l == 1) ? sb1 : (l == 2) ? sb2 : sb3;
            u32 dst = bb + s_pre[j][wave][l] + pre;
            float4 rr = r0[k];
            float v = (l == 0) ? rr.x : (l == 1) ? rr.y
                                     : (l == 2) ? rr.z : rr.w;
            float adj = (v > 0.f) ? (v * INV_M - 0.5f) : (v * 4.00001f - 0.5f);
            if (l == 0) rr.x = adj;
            else if (l == 1) rr.y = adj;
            else if (l == 2) rr.z = adj;
            else rr.w = adj;
            out_data[dst] = rr;
            float mx = fmaxf(fmaxf(rr.x, rr.y), fmaxf(rr.z, rr.w));
            float se = __expf(rr.x - mx) + __expf(rr.y - mx) +
                       __expf(rr.z - mx) + __expf(rr.w - mx);
            loss += (mx + __logf(se)) - adj;
        }
    }
#pragma unroll
    for (int k = 0; k < 8; ++k) {
        int j = 8 + k;
        if ((vmask >> j) & 1) {
            int l = (packed >> (2 * j)) & 3;
            u32 pre = (preP[j >> 2] >> (8 * (j & 3))) & 255u;
            u32 bb = (l == 0) ? sb0 : (l == 1) ? sb1 : (l == 2) ? sb2 : sb3;
            u32 dst = bb + s_pre[j][wave][l] + pre;
            float4 rr = r1[k];
            float v = (l == 0) ? rr.x : (l == 1) ? rr.y
                                     : (l == 2) ? rr.z : rr.w;
            float adj = (v > 0.f) ? (v * INV_M - 0.5f) : (v * 4.00001f - 0.5f);
            if (l == 0) rr.x = adj;
            else if (l == 1) rr.y = adj;
            else if (l == 2) rr.z = adj;
            else rr.w = adj;
            out_data[dst] = rr;
            float mx = fmaxf(fmaxf(rr.x, rr.y), fmaxf(rr.z, rr.w));
            float se = __expf(rr.x - mx) + __expf(rr.y - mx) +
                       __expf(rr.z - mx) + __expf(rr.w - mx);
            loss += (mx + __logf(se)) - adj;
        }
    }

    {
        int t4base = base >> 2;
#pragma unroll
        for (int k = 0; k < 4; ++k) {
            int t4 = t4base + k * BLOCK + tid;
            int j0 = t4 * 4;
            if (j0 + 3 < N) {
                u32 j0u = (u32)j0;
                float4 rl;
                rl.x = (float)((j0u >= cb1) + (j0u >= cb2) + (j0u >= cb3));
                rl.y = (float)((j0u + 1 >= cb1) + (j0u + 1 >= cb2) + (j0u + 1 >= cb3));
                rl.z = (float)((j0u + 2 >= cb1) + (j0u + 2 >= cb2) + (j0u + 2 >= cb3));
                rl.w = (float)((j0u + 3 >= cb1) + (j0u + 3 >= cb2) + (j0u + 3 >= cb3));
                ((float4*)out_label)[t4] = rl;
            } else {
                for (int q = 0; q < 4; ++q) {
                    int jj = j0 + q;
                    if (jj >= 0 && jj < N) {
                        u32 ju = (u32)jj;
                        out_label[jj] =
                            (float)((ju >= cb1) + (ju >= cb2) + (ju >= cb3));
                    }
                }
            }
        }
    }

    double d = (double)loss;
#pragma unroll
    for (int off = 32; off > 0; off >>= 1) d += __shfl_down(d, off, 64);
    if (lane == 0) s_w[wave] = d;
    __syncthreads();
    if (tid == 0) atomicAdd(acc, s_w[0] + s_w[1] + s_w[2] + s_w[3]);
}

__global__ void finalize_kernel(const double* __restrict__ acc, int N,
                                float* __restrict__ out_loss) {
    *out_loss = (float)(*acc / (double)N);
}

// ---------------------------------------------------------------------------
extern "C" void kernel_launch(void* const* d_in, const int* in_sizes, int n_in,
                              void* d_out, int out_size, void* d_ws,
                              size_t ws_size, hipStream_t stream) {
    const float* data = (const float*)d_in[0];
    const int* labels = (const int*)d_in[1];
    int N = in_sizes[1];

    float* out = (float*)d_out;
    float4* out_data = (float4*)out;               // N*4 floats
    float* out_label = out + (size_t)N * 4;        // N
    float* out_loss = out + (size_t)N * 5;         // 1

    int nbC = (N + CHUNK_C - 1) / CHUNK_C;
    int nbF = (N + CHUNK_F - 1) / CHUNK_F;

    // Workspace layout (both paths).
    u32* histC = (u32*)d_ws;                       // nbC*4
    u32* histF = histC + (size_t)nbC * 4;          // nbF*4
    u32* plabF = histF + (size_t)nbF * 4;          // nbF*BLOCK
    double* acc =
        (double*)(((uintptr_t)(plabF + (size_t)nbF * BLOCK) + 15) &
                  ~(uintptr_t)15);
    u32* done = (u32*)(acc + 1);

    bool coop = false;
    if (nbC <= 1024) {  // co-residency: 256 CU x 4 blocks @ launch_bounds(256,4)
        const float4* d4 = (const float4*)data;
        void* args[] = {(void*)&d4,       (void*)&labels,   (void*)&N,
                        (void*)&nbC,      (void*)&histC,    (void*)&out_data,
                        (void*)&out_label, (void*)&acc,     (void*)&done,
                        (void*)&out_loss};
        hipError_t e = hipLaunchCooperativeKernel(
            (const void*)fused_kernel, dim3(nbC), dim3(BLOCK), args, 0, stream);
        coop = (e == hipSuccess);
        if (!coop) (void)hipGetLastError();  // clear sticky error
    }

    if (!coop) {
        hist_kernel<<<nbF, BLOCK, 0, stream>>>(labels, N, histF, plabF, acc);
        sort_kernel<<<nbF, BLOCK, 0, stream>>>((const float4*)data, plabF, N,
                                               nbF, histF, out_data, out_label,
                                               acc);
        finalize_kernel<<<1, 1, 0, stream>>>(acc, N, out_loss);
    }
}

// Round 4
// 328.434 us; speedup vs baseline: 1.4088x; 1.4088x over previous
//
#include <hip/hip_runtime.h>
#include <math.h>
#include <stdint.h>

typedef unsigned int u32;
typedef unsigned long long u64;
typedef float f32x4 __attribute__((ext_vector_type(4)));

#define BLOCK 256
#define ITEMS 16
#define CHUNK (BLOCK * ITEMS)  // 4096 elements per block

// ---------------------------------------------------------------------------
// Pass 1: per-block class histograms + 2-bit packed labels in sort's exact
// access pattern (one u32 per (block, tid)). Zero-inits loss accumulator.
// ---------------------------------------------------------------------------
__global__ void __launch_bounds__(BLOCK)
hist_kernel(const int* __restrict__ labels, int N,
            u32* __restrict__ hist, u32* __restrict__ plab,
            double* __restrict__ acc) {
    __shared__ u32 s_cnt[4][4];  // [wave][class]
    int tid = threadIdx.x;
    int lane = tid & 63;
    int wave = tid >> 6;
    int base = blockIdx.x * CHUNK;
    u32 packed = 0;
    u32 c0 = 0, c1 = 0, c2 = 0, c3 = 0;
#pragma unroll
    for (int j = 0; j < ITEMS; ++j) {
        int idx = base + j * BLOCK + tid;
        bool valid = idx < N;
        int l = valid ? labels[idx] : 0;
        packed |= (u32)l << (2 * j);
        c0 += (valid && l == 0);
        c1 += (valid && l == 1);
        c2 += (valid && l == 2);
        c3 += (valid && l == 3);
    }
    plab[blockIdx.x * BLOCK + tid] = packed;
#pragma unroll
    for (int off = 32; off > 0; off >>= 1) {
        c0 += (u32)__shfl_down((int)c0, off, 64);
        c1 += (u32)__shfl_down((int)c1, off, 64);
        c2 += (u32)__shfl_down((int)c2, off, 64);
        c3 += (u32)__shfl_down((int)c3, off, 64);
    }
    if (lane == 0) {
        s_cnt[wave][0] = c0; s_cnt[wave][1] = c1;
        s_cnt[wave][2] = c2; s_cnt[wave][3] = c3;
    }
    __syncthreads();
    if (tid < 4)
        hist[blockIdx.x * 4 + tid] =
            s_cnt[0][tid] + s_cnt[1][tid] + s_cnt[2][tid] + s_cnt[3][tid];
    if (blockIdx.x == 0 && tid == 0) *acc = 0.0;
}

// ---------------------------------------------------------------------------
// Pass 2: packed-label load + per-block hist prefix (L2-hot, issued BEFORE
// the streaming loads so its self-waiting loop doesn't drain them) + real
// 16-deep float4 prefetch (launch_bounds(256,4) -> 128 VGPR cap so r[16]
// stays in registers) + ballot ranks + scatter with NON-TEMPORAL stores
// (outputs never re-read; keeps inputs L3-resident) + fused analytic label
// write + loss.
// ---------------------------------------------------------------------------
struct SortShared {
    u32 s_pre[ITEMS][4][4];  // [iter][wave][class] -> excl prefix
    u32 s_red[4][8];         // [wave][bef.xyzw, tot.xyzw]
    u32 s_bc[8];             // sb0..sb3, cb1..cb3
    double s_w[4];
};

template <bool FULL>
__device__ __forceinline__ void
sort_body(SortShared& sh, const float4* __restrict__ data,
          const u32* __restrict__ plab, int N, int nb,
          const u32* __restrict__ hist, float4* __restrict__ out_data,
          float* __restrict__ out_label, double* __restrict__ acc) {
    int tid = threadIdx.x;
    int lane = tid & 63;
    int wave = tid >> 6;
    int base = blockIdx.x * CHUNK;

    // --- One dword: all 16 labels for this thread.
    u32 packed = plab[blockIdx.x * BLOCK + tid];
    u32 vmask;
    if (FULL) {
        vmask = 0xFFFFu;
    } else {
        int rem = N - base - tid;
        vmask = 0;
#pragma unroll
        for (int j = 0; j < ITEMS; ++j)
            vmask |= (u32)(j * BLOCK < rem) << j;
    }

    // --- Per-block hist prefix + totals (uint4, L2-hot). Self-waiting loop:
    //     must run BEFORE the 16 streaming loads (vmcnt retires in-order).
    uint4 bef = make_uint4(0, 0, 0, 0), tot = make_uint4(0, 0, 0, 0);
    {
        const uint4* h4 = (const uint4*)hist;
        u32 myb = blockIdx.x;
        for (int bb = tid; bb < nb; bb += BLOCK) {
            uint4 h = h4[bb];
            tot.x += h.x; tot.y += h.y; tot.z += h.z; tot.w += h.w;
            if ((u32)bb < myb) {
                bef.x += h.x; bef.y += h.y; bef.z += h.z; bef.w += h.w;
            }
        }
    }

    // --- Issue ALL 16 data loads; they retire under the rank phase's VALU.
    float4 r[ITEMS];
#pragma unroll
    for (int j = 0; j < ITEMS; ++j) {
        if (FULL || ((vmask >> j) & 1)) r[j] = data[base + j * BLOCK + tid];
    }

    // --- Phase A: ballots -> per-wave counts (LDS) + per-lane rank in regs.
    u64 ltm = (1ULL << lane) - 1ULL;
    u32 preP[ITEMS / 4] = {0, 0, 0, 0};
#pragma unroll
    for (int j = 0; j < ITEMS; ++j) {
        bool valid = FULL || ((vmask >> j) & 1);
        int l = (packed >> (2 * j)) & 3;
        u64 m0 = __ballot(valid && l == 0);
        u64 m1 = __ballot(valid && l == 1);
        u64 m2 = __ballot(valid && l == 2);
        u64 m3 = __ballot(valid && l == 3);
        if (lane == 0) {
            sh.s_pre[j][wave][0] = (u32)__popcll(m0);
            sh.s_pre[j][wave][1] = (u32)__popcll(m1);
            sh.s_pre[j][wave][2] = (u32)__popcll(m2);
            sh.s_pre[j][wave][3] = (u32)__popcll(m3);
        }
        u64 mm = (l == 0) ? m0 : (l == 1) ? m1 : (l == 2) ? m2 : m3;
        preP[j >> 2] |= ((u32)__popcll(mm & ltm)) << (8 * (j & 3));
    }

    // --- Wave-reduce bef/tot into LDS.
#pragma unroll
    for (int off = 32; off > 0; off >>= 1) {
        bef.x += (u32)__shfl_down((int)bef.x, off, 64);
        bef.y += (u32)__shfl_down((int)bef.y, off, 64);
        bef.z += (u32)__shfl_down((int)bef.z, off, 64);
        bef.w += (u32)__shfl_down((int)bef.w, off, 64);
        tot.x += (u32)__shfl_down((int)tot.x, off, 64);
        tot.y += (u32)__shfl_down((int)tot.y, off, 64);
        tot.z += (u32)__shfl_down((int)tot.z, off, 64);
        tot.w += (u32)__shfl_down((int)tot.w, off, 64);
    }
    if (lane == 0) {
        sh.s_red[wave][0] = bef.x; sh.s_red[wave][1] = bef.y;
        sh.s_red[wave][2] = bef.z; sh.s_red[wave][3] = bef.w;
        sh.s_red[wave][4] = tot.x; sh.s_red[wave][5] = tot.y;
        sh.s_red[wave][6] = tot.z; sh.s_red[wave][7] = tot.w;
    }
    __syncthreads();

    // --- Scan: wave w owns class w; 64 entries in (j, wave) order.
    {
        int c = wave;
        int e = lane;
        u32 x = sh.s_pre[e >> 2][e & 3][c];
        u32 orig = x;
#pragma unroll
        for (int off = 1; off < 64; off <<= 1) {
            u32 v = (u32)__shfl_up((int)x, off, 64);
            if (lane >= off) x += v;
        }
        sh.s_pre[e >> 2][e & 3][c] = x - orig;  // exclusive prefix in block
    }
    if (tid == 0) {
        u32 B0 = sh.s_red[0][0] + sh.s_red[1][0] + sh.s_red[2][0] + sh.s_red[3][0];
        u32 B1 = sh.s_red[0][1] + sh.s_red[1][1] + sh.s_red[2][1] + sh.s_red[3][1];
        u32 B2 = sh.s_red[0][2] + sh.s_red[1][2] + sh.s_red[2][2] + sh.s_red[3][2];
        u32 B3 = sh.s_red[0][3] + sh.s_red[1][3] + sh.s_red[2][3] + sh.s_red[3][3];
        u32 T0 = sh.s_red[0][4] + sh.s_red[1][4] + sh.s_red[2][4] + sh.s_red[3][4];
        u32 T1 = sh.s_red[0][5] + sh.s_red[1][5] + sh.s_red[2][5] + sh.s_red[3][5];
        u32 T2 = sh.s_red[0][6] + sh.s_red[1][6] + sh.s_red[2][6] + sh.s_red[3][6];
        u32 cb1 = T0, cb2 = T0 + T1, cb3 = T0 + T1 + T2;
        sh.s_bc[0] = B0;       sh.s_bc[1] = cb1 + B1;
        sh.s_bc[2] = cb2 + B2; sh.s_bc[3] = cb3 + B3;
        sh.s_bc[4] = cb1; sh.s_bc[5] = cb2; sh.s_bc[6] = cb3;
    }
    __syncthreads();

    u32 sb0 = sh.s_bc[0], sb1 = sh.s_bc[1], sb2 = sh.s_bc[2], sb3 = sh.s_bc[3];
    u32 cb1 = sh.s_bc[4], cb2 = sh.s_bc[5], cb3 = sh.s_bc[6];

    // --- Process all 16: adjust + NT scatter + loss.
    const float INV_M = 0.249999375f;  // 1/4.00001
    float loss = 0.f;
#pragma unroll
    for (int j = 0; j < ITEMS; ++j) {
        if (FULL || ((vmask >> j) & 1)) {
            int l = (packed >> (2 * j)) & 3;
            u32 pre = (preP[j >> 2] >> (8 * (j & 3))) & 255u;
            u32 bb = (l == 0) ? sb0 : (l == 1) ? sb1 : (l == 2) ? sb2 : sb3;
            u32 dst = bb + sh.s_pre[j][wave][l] + pre;
            float4 rr = r[j];
            float v = (l == 0) ? rr.x : (l == 1) ? rr.y
                                     : (l == 2) ? rr.z : rr.w;
            float adj = (v > 0.f) ? (v * INV_M - 0.5f) : (v * 4.00001f - 0.5f);
            if (l == 0) rr.x = adj;
            else if (l == 1) rr.y = adj;
            else if (l == 2) rr.z = adj;
            else rr.w = adj;
            f32x4 st = {rr.x, rr.y, rr.z, rr.w};
            __builtin_nontemporal_store(st, (f32x4*)&out_data[dst]);
            float mx = fmaxf(fmaxf(rr.x, rr.y), fmaxf(rr.z, rr.w));
            float se = __expf(rr.x - mx) + __expf(rr.y - mx) +
                       __expf(rr.z - mx) + __expf(rr.w - mx);
            loss += (mx + __logf(se)) - adj;  // -log p_true
        }
    }

    // --- Fused analytic label write (non-temporal; never re-read).
    {
        int t4base = base >> 2;
#pragma unroll
        for (int k = 0; k < 4; ++k) {
            int t4 = t4base + k * BLOCK + tid;
            int j0 = t4 * 4;
            if (FULL || j0 + 3 < N) {
                u32 j0u = (u32)j0;
                f32x4 rl;
                rl.x = (float)((j0u >= cb1) + (j0u >= cb2) + (j0u >= cb3));
                rl.y = (float)((j0u + 1 >= cb1) + (j0u + 1 >= cb2) + (j0u + 1 >= cb3));
                rl.z = (float)((j0u + 2 >= cb1) + (j0u + 2 >= cb2) + (j0u + 2 >= cb3));
                rl.w = (float)((j0u + 3 >= cb1) + (j0u + 3 >= cb2) + (j0u + 3 >= cb3));
                __builtin_nontemporal_store(rl, (f32x4*)&out_label[j0]);
            } else {
                for (int q = 0; q < 4; ++q) {
                    int jj = j0 + q;
                    if (jj >= 0 && jj < N) {
                        u32 ju = (u32)jj;
                        out_label[jj] =
                            (float)((ju >= cb1) + (ju >= cb2) + (ju >= cb3));
                    }
                }
            }
        }
    }

    // --- Block-reduce loss in double, one atomic per block.
    double d = (double)loss;
#pragma unroll
    for (int off = 32; off > 0; off >>= 1) d += __shfl_down(d, off, 64);
    if (lane == 0) sh.s_w[wave] = d;
    __syncthreads();
    if (tid == 0) atomicAdd(acc, sh.s_w[0] + sh.s_w[1] + sh.s_w[2] + sh.s_w[3]);
}

__global__ void __launch_bounds__(BLOCK, 4)  // 4 waves/EU min -> 128 VGPR cap
sort_kernel(const float4* __restrict__ data, const u32* __restrict__ plab,
            int N, int nb, const u32* __restrict__ hist,
            float4* __restrict__ out_data, float* __restrict__ out_label,
            double* __restrict__ acc) {
    __shared__ SortShared sh;
    int base = blockIdx.x * CHUNK;
    if (base + CHUNK <= N) {
        sort_body<true>(sh, data, plab, N, nb, hist, out_data, out_label, acc);
    } else {
        sort_body<false>(sh, data, plab, N, nb, hist, out_data, out_label, acc);
    }
}

// ---------------------------------------------------------------------------
// Pass 3: loss finalize only (1 thread).
// ---------------------------------------------------------------------------
__global__ void finalize_kernel(const double* __restrict__ acc, int N,
                                float* __restrict__ out_loss) {
    *out_loss = (float)(*acc / (double)N);
}

// ---------------------------------------------------------------------------
extern "C" void kernel_launch(void* const* d_in, const int* in_sizes, int n_in,
                              void* d_out, int out_size, void* d_ws,
                              size_t ws_size, hipStream_t stream) {
    const float* data = (const float*)d_in[0];
    const int* labels = (const int*)d_in[1];
    int N = in_sizes[1];
    int nb = (N + CHUNK - 1) / CHUNK;

    u32* hist = (u32*)d_ws;                     // nb*4 u32
    u32* plab = hist + (size_t)nb * 4;          // nb*BLOCK u32 (packed labels)
    double* acc =
        (double*)(((uintptr_t)(plab + (size_t)nb * BLOCK) + 15) &
                  ~(uintptr_t)15);

    float* out = (float*)d_out;
    float* out_data = out;                   // N*4
    float* out_label = out + (size_t)N * 4;  // N
    float* out_loss = out + (size_t)N * 5;   // 1

    hist_kernel<<<nb, BLOCK, 0, stream>>>(labels, N, hist, plab, acc);
    sort_kernel<<<nb, BLOCK, 0, stream>>>((const float4*)data, plab, N, nb,
                                          hist, (float4*)out_data, out_label,
                                          acc);
    finalize_kernel<<<1, 1, 0, stream>>>(acc, N, out_loss);
}